// Round 5
// baseline (9349.351 us; speedup 1.0000x reference)
//
#include <hip/hip_runtime.h>

#define T_LEN 8192
#define N_NODES 33
#define N_EDGES 64
#define DIM_IN 3
#define D_H 64
#define D_LSTM 128
#define N_CLS 5
#define TB 4   // timesteps per block in kernel 1

// ---------------------------------------------------------------------------
// Kernel 1: graph conv x2 + relu + mean over nodes + input-side LSTM projection
// Writes A[t][o] = seq_t @ W_ih.T + b_ih + b_hh   (T x 512)
// ---------------------------------------------------------------------------
__global__ __launch_bounds__(64, 2) void gnn_proj_kernel(
    const float* __restrict__ x,        // (T,33,3)
    const int*   __restrict__ esrc,     // (64,)
    const int*   __restrict__ edst,     // (64,)
    const float* __restrict__ W_rel1,   // (64,3)
    const float* __restrict__ b_rel1,   // (64,)
    const float* __restrict__ W_root1,  // (64,3)
    const float* __restrict__ W_rel2,   // (64,64)
    const float* __restrict__ b_rel2,   // (64,)
    const float* __restrict__ W_root2,  // (64,64)
    const float* __restrict__ W_ih,     // (512,64)
    const float* __restrict__ b_ih,     // (512,)
    const float* __restrict__ b_hh,     // (512,)
    float* __restrict__ A)              // (T,512)  [workspace]
{
    const int t0 = blockIdx.x * TB;
    const int j  = threadIdx.x;   // 0..63

    __shared__ __align__(16) float x_s[N_NODES][DIM_IN];
    __shared__ __align__(16) float agg1[N_NODES][DIM_IN];
    __shared__ __align__(16) float h1[N_NODES][D_H];
    __shared__ __align__(16) float agg2[N_NODES][D_H];
    __shared__ __align__(16) float seq_s[TB][D_H];
    __shared__ int es[N_EDGES], ed[N_EDGES];

    es[j] = esrc[j];
    ed[j] = edst[j];

    const float wr1_0 = W_rel1[j*3+0], wr1_1 = W_rel1[j*3+1], wr1_2 = W_rel1[j*3+2];
    const float wt1_0 = W_root1[j*3+0], wt1_1 = W_root1[j*3+1], wt1_2 = W_root1[j*3+2];
    const float br1 = b_rel1[j];
    const float br2 = b_rel2[j];

    float wr2[D_H], wt2[D_H];
    #pragma unroll
    for (int k = 0; k < D_H; ++k) {
        wr2[k] = W_rel2[j*D_H + k];
        wt2[k] = W_root2[j*D_H + k];
    }

    for (int tt = 0; tt < TB; ++tt) {
        const int t = t0 + tt;
        __syncthreads();

        const float* xt = x + (size_t)t * (N_NODES * DIM_IN);
        for (int i = j; i < N_NODES * DIM_IN; i += 64) x_s[0][i] = xt[i];
        __syncthreads();

        if (j < N_NODES) {
            float a0 = 0.f, a1 = 0.f, a2 = 0.f;
            for (int e = 0; e < N_EDGES; ++e) {
                if (ed[e] == j) {
                    a0 += x_s[es[e]][0];
                    a1 += x_s[es[e]][1];
                    a2 += x_s[es[e]][2];
                }
            }
            agg1[j][0] = a0; agg1[j][1] = a1; agg1[j][2] = a2;
        }
        __syncthreads();

        for (int n = 0; n < N_NODES; ++n) {
            float v = br1
                + agg1[n][0]*wr1_0 + agg1[n][1]*wr1_1 + agg1[n][2]*wr1_2
                + x_s[n][0]*wt1_0  + x_s[n][1]*wt1_1  + x_s[n][2]*wt1_2;
            h1[n][j]  = v;
            agg2[n][j] = 0.f;
        }
        __syncthreads();

        for (int e = 0; e < N_EDGES; ++e) {
            agg2[ed[e]][j] += h1[es[e]][j];
        }
        __syncthreads();

        float seqv = 0.f;
        for (int n = 0; n < N_NODES; ++n) {
            const float4* ag4 = (const float4*)agg2[n];
            const float4* h4  = (const float4*)h1[n];
            float acc0 = br2, acc1 = 0.f, acc2 = 0.f, acc3 = 0.f;
            #pragma unroll
            for (int k4 = 0; k4 < D_H/4; ++k4) {
                float4 av = ag4[k4];
                float4 hv = h4[k4];
                acc0 += av.x * wr2[4*k4+0] + hv.x * wt2[4*k4+0];
                acc1 += av.y * wr2[4*k4+1] + hv.y * wt2[4*k4+1];
                acc2 += av.z * wr2[4*k4+2] + hv.z * wt2[4*k4+2];
                acc3 += av.w * wr2[4*k4+3] + hv.w * wt2[4*k4+3];
            }
            float acc = (acc0 + acc1) + (acc2 + acc3);
            seqv += fmaxf(acc, 0.f);
        }
        seq_s[tt][j] = seqv * (1.0f / 33.0f);
    }
    __syncthreads();

    #pragma unroll
    for (int m = 0; m < 8; ++m) {
        const int o = m * 64 + j;
        const float bias = b_ih[o] + b_hh[o];
        const float4* w4 = (const float4*)(W_ih + (size_t)o * D_H);
        float acc[TB];
        #pragma unroll
        for (int tt = 0; tt < TB; ++tt) acc[tt] = bias;
        #pragma unroll
        for (int k4 = 0; k4 < D_H/4; ++k4) {
            float4 wv = w4[k4];
            #pragma unroll
            for (int tt = 0; tt < TB; ++tt) {
                const float4* s4 = (const float4*)seq_s[tt];
                float4 sv = s4[k4];
                acc[tt] += sv.x*wv.x + sv.y*wv.y + sv.z*wv.z + sv.w*wv.w;
            }
        }
        #pragma unroll
        for (int tt = 0; tt < TB; ++tt) {
            A[(size_t)(t0 + tt) * 512 + o] = acc[tt];
        }
    }
}

// ---------------------------------------------------------------------------
// Kernel 2: sequential LSTM, single block (1 CU), 1024 threads = 16 waves,
// 4 waves/SIMD (128-VGPR budget).
//
// Thread (q, kq): owns ALL FOUR gate rows of h_q {q,128+q,256+q,384+q}
// restricted to K-chunk [16*kq, 16*kq+16), kq in 0..7.
//   lane bits: b0,b1 -> kq[0:2], b3 -> kq[2];  b2 -> idx[0], b4,b5 -> idx[1:3]
//   q = wave*8 + idx
// Weights: 16 named float4 = 64 VGPRs (asm-pinned) -> fits the 128 budget,
// no spill (rounds 2-4 failure mode).
// K-reduction over the 8 kq = pure-VALU DPP butterfly (quad_perm xor1/xor2 +
// row_ror:8 == xor8) -> zero ds_bpermute. All 4 gates land in the kq==0
// thread -> nonlinearity computed ONCE per q (no redundancy, no exchange).
// h in LDS is PERMUTED (flat = i4*32 + kq*4 + j  <->  h[kq*16 + i4*4 + j]) so
// each ds_read_b128 hits 8 consecutive 16B chunks = all 32 banks once ->
// conflict-free broadcast. h double-buffered, ONE barrier per step.
// ---------------------------------------------------------------------------
__device__ __forceinline__ float sigmoid_f(float v) {
    return 1.0f / (1.0f + __expf(-v));
}
__device__ __forceinline__ float tanh_f(float v) {
    return 1.0f - 2.0f / (1.0f + __expf(2.0f * v));
}

// butterfly add over lane-xor distance via DPP (VALU pipe, no LDS)
__device__ __forceinline__ float dpp_add_x1(float v) {   // lane ^ 1
    int s = __builtin_amdgcn_update_dpp(0, __float_as_int(v), 0xB1, 0xf, 0xf, true);
    return v + __int_as_float(s);
}
__device__ __forceinline__ float dpp_add_x2(float v) {   // lane ^ 2
    int s = __builtin_amdgcn_update_dpp(0, __float_as_int(v), 0x4E, 0xf, 0xf, true);
    return v + __int_as_float(s);
}
__device__ __forceinline__ float dpp_add_x8(float v) {   // lane ^ 8 (row_ror:8)
    int s = __builtin_amdgcn_update_dpp(0, __float_as_int(v), 0x128, 0xf, 0xf, true);
    return v + __int_as_float(s);
}
__device__ __forceinline__ float red8(float v) {
    return dpp_add_x8(dpp_add_x2(dpp_add_x1(v)));
}

#define R4(M) M(0) M(1) M(2) M(3)

__global__ __launch_bounds__(1024, 4)
void lstm_kernel(
    const float* __restrict__ A,      // (T,512)
    const float* __restrict__ W_hh,   // (512,128)
    const float* __restrict__ W_fc,   // (5,128)
    const float* __restrict__ b_fc,   // (5,)
    float* __restrict__ out)          // (5,)
{
    const int tid  = threadIdx.x;            // 0..1023
    const int lane = tid & 63;
    const int wave = tid >> 6;
    const int kq   = (lane & 3) | ((lane >> 1) & 4);        // bits 0,1,3
    const int idx  = ((lane >> 2) & 1) | ((lane >> 3) & 6); // bits 2,4,5
    const int q    = wave * 8 + idx;          // h index 0..127
    const int kbase = kq * 16;                // K-chunk start
    const bool owner = (kq == 0);

    __shared__ __align__(16) float h_s[2][D_LSTM];   // PERMUTED layout, dbuf

    // ---- weights: 4 gate rows x 16 K = 16 named float4 (64 VGPRs), pinned ----
    const float4* Wi4 = (const float4*)(W_hh + (size_t)q            * D_LSTM + kbase);
    const float4* Wf4 = (const float4*)(W_hh + (size_t)(128 + q)    * D_LSTM + kbase);
    const float4* Wg4 = (const float4*)(W_hh + (size_t)(256 + q)    * D_LSTM + kbase);
    const float4* Wo4 = (const float4*)(W_hh + (size_t)(384 + q)    * D_LSTM + kbase);
#define DECLW(i) float4 wi##i = Wi4[i]; float4 wf##i = Wf4[i]; \
                 float4 wg##i = Wg4[i]; float4 wo##i = Wo4[i];
    R4(DECLW)
#undef DECLW
#define PINW(i) asm volatile("" : "+v"(wi##i.x), "+v"(wi##i.y), "+v"(wi##i.z), "+v"(wi##i.w), \
                                  "+v"(wf##i.x), "+v"(wf##i.y), "+v"(wf##i.z), "+v"(wf##i.w), \
                                  "+v"(wg##i.x), "+v"(wg##i.y), "+v"(wg##i.z), "+v"(wg##i.w), \
                                  "+v"(wo##i.x), "+v"(wo##i.y), "+v"(wo##i.z), "+v"(wo##i.w));
    R4(PINW)
#undef PINW

    if (tid < 2 * D_LSTM) ((float*)h_s)[tid] = 0.f;   // h_{-1} = 0 (both bufs)
    __syncthreads();

    float c = 0.f;                       // cell state, lives in kq==0 threads
    const float* Aq = A + q;

    // prefetch A[0] gate biases for this q (unmasked: dup addresses coalesce)
    float ai = Aq[0];
    float af = Aq[128];
    float ag = Aq[256];
    float ao = Aq[384];

    for (int t = 0; t < T_LEN; ++t) {
        const float ai_c = ai, af_c = af, ag_c = ag, ao_c = ao;
        const size_t tn = (size_t)((t + 1) & (T_LEN - 1)) * 512;
        ai = Aq[tn];           // prefetch next step (hidden under FMA block)
        af = Aq[tn + 128];
        ag = Aq[tn + 256];
        ao = Aq[tn + 384];

        // ---- permuted broadcast read of h chunk: 4x conflict-free b128 ----
        const float4* hb = (const float4*)h_s[t & 1];
        float4 hv0 = hb[kq];
        float4 hv1 = hb[8 + kq];
        float4 hv2 = hb[16 + kq];
        float4 hv3 = hb[24 + kq];

        // ---- 64 FMAs: 4 gates x 16 K (4 independent chains) ----
        float pi = 0.f, pf = 0.f, pg = 0.f, po = 0.f;
#define FMA4(hv, i) \
        pi = __builtin_fmaf(hv.x, wi##i.x, pi); pf = __builtin_fmaf(hv.x, wf##i.x, pf); \
        pg = __builtin_fmaf(hv.x, wg##i.x, pg); po = __builtin_fmaf(hv.x, wo##i.x, po); \
        pi = __builtin_fmaf(hv.y, wi##i.y, pi); pf = __builtin_fmaf(hv.y, wf##i.y, pf); \
        pg = __builtin_fmaf(hv.y, wg##i.y, pg); po = __builtin_fmaf(hv.y, wo##i.y, po); \
        pi = __builtin_fmaf(hv.z, wi##i.z, pi); pf = __builtin_fmaf(hv.z, wf##i.z, pf); \
        pg = __builtin_fmaf(hv.z, wg##i.z, pg); po = __builtin_fmaf(hv.z, wo##i.z, po); \
        pi = __builtin_fmaf(hv.w, wi##i.w, pi); pf = __builtin_fmaf(hv.w, wf##i.w, pf); \
        pg = __builtin_fmaf(hv.w, wg##i.w, pg); po = __builtin_fmaf(hv.w, wo##i.w, po);
        FMA4(hv0, 0)
        FMA4(hv1, 1)
        FMA4(hv2, 2)
        FMA4(hv3, 3)
#undef FMA4

        // ---- K-reduction over 8 kq: pure-VALU DPP butterfly ----
        const float gi = ai_c + red8(pi);
        const float gf = af_c + red8(pf);
        const float gg = ag_c + red8(pg);
        const float go = ao_c + red8(po);

        // ---- nonlinearity: ONCE per q, in the kq==0 thread ----
        if (owner) {
            const float si = sigmoid_f(gi);
            const float sf = sigmoid_f(gf);
            const float so = sigmoid_f(go);
            const float tg = tanh_f(gg);
            c = sf * c + si * tg;
            const float hv = so * tanh_f(c);
            // write to permuted position of buffer (t+1)&1
            const int p = ((q & 15) >> 2) * 32 + (q >> 4) * 4 + (q & 3);
            h_s[(t + 1) & 1][p] = hv;
        }
        __syncthreads();    // ONE barrier per step (dbuf covers the rest)
    }

    // final FC: out = hT @ W_fc.T + b_fc  (final h in buffer 0, permuted)
    if (tid < N_CLS) {
        float acc = b_fc[tid];
        #pragma unroll
        for (int k = 0; k < D_LSTM; ++k) {
            const int p = ((k & 15) >> 2) * 32 + (k >> 4) * 4 + (k & 3);
            acc += h_s[0][p] * W_fc[tid * D_LSTM + k];
        }
        out[tid] = acc;
    }
}

// ---------------------------------------------------------------------------
extern "C" void kernel_launch(void* const* d_in, const int* in_sizes, int n_in,
                              void* d_out, int out_size, void* d_ws, size_t ws_size,
                              hipStream_t stream) {
    const float* x       = (const float*)d_in[0];
    const int*   esrc    = (const int*)  d_in[1];
    const int*   edst    = (const int*)  d_in[2];
    const float* W_rel1  = (const float*)d_in[3];
    const float* b_rel1  = (const float*)d_in[4];
    const float* W_root1 = (const float*)d_in[5];
    const float* W_rel2  = (const float*)d_in[6];
    const float* b_rel2  = (const float*)d_in[7];
    const float* W_root2 = (const float*)d_in[8];
    const float* W_ih    = (const float*)d_in[9];
    const float* W_hh    = (const float*)d_in[10];
    const float* b_ih    = (const float*)d_in[11];
    const float* b_hh    = (const float*)d_in[12];
    const float* W_fc    = (const float*)d_in[13];
    const float* b_fc    = (const float*)d_in[14];

    float* out = (float*)d_out;
    float* A   = (float*)d_ws;   // (T,512) f32 = 16 MB

    gnn_proj_kernel<<<T_LEN / TB, 64, 0, stream>>>(
        x, esrc, edst, W_rel1, b_rel1, W_root1,
        W_rel2, b_rel2, W_root2, W_ih, b_ih, b_hh, A);

    lstm_kernel<<<1, 1024, 0, stream>>>(A, W_hh, W_fc, b_fc, out);
}

// Round 6
// 8806.806 us; speedup vs baseline: 1.0616x; 1.0616x over previous
//
#include <hip/hip_runtime.h>

#define T_LEN 8192
#define N_NODES 33
#define N_EDGES 64
#define DIM_IN 3
#define D_H 64
#define D_LSTM 128
#define N_CLS 5
#define TB 4   // timesteps per block in kernel 1

// ---------------------------------------------------------------------------
// Kernel 1: graph conv x2 + relu + mean over nodes + input-side LSTM projection
// Writes A[t][o] = seq_t @ W_ih.T + b_ih + b_hh   (T x 512)
// ---------------------------------------------------------------------------
__global__ __launch_bounds__(64, 2) void gnn_proj_kernel(
    const float* __restrict__ x,        // (T,33,3)
    const int*   __restrict__ esrc,     // (64,)
    const int*   __restrict__ edst,     // (64,)
    const float* __restrict__ W_rel1,   // (64,3)
    const float* __restrict__ b_rel1,   // (64,)
    const float* __restrict__ W_root1,  // (64,3)
    const float* __restrict__ W_rel2,   // (64,64)
    const float* __restrict__ b_rel2,   // (64,)
    const float* __restrict__ W_root2,  // (64,64)
    const float* __restrict__ W_ih,     // (512,64)
    const float* __restrict__ b_ih,     // (512,)
    const float* __restrict__ b_hh,     // (512,)
    float* __restrict__ A)              // (T,512)  [workspace]
{
    const int t0 = blockIdx.x * TB;
    const int j  = threadIdx.x;   // 0..63

    __shared__ __align__(16) float x_s[N_NODES][DIM_IN];
    __shared__ __align__(16) float agg1[N_NODES][DIM_IN];
    __shared__ __align__(16) float h1[N_NODES][D_H];
    __shared__ __align__(16) float agg2[N_NODES][D_H];
    __shared__ __align__(16) float seq_s[TB][D_H];
    __shared__ int es[N_EDGES], ed[N_EDGES];

    es[j] = esrc[j];
    ed[j] = edst[j];

    const float wr1_0 = W_rel1[j*3+0], wr1_1 = W_rel1[j*3+1], wr1_2 = W_rel1[j*3+2];
    const float wt1_0 = W_root1[j*3+0], wt1_1 = W_root1[j*3+1], wt1_2 = W_root1[j*3+2];
    const float br1 = b_rel1[j];
    const float br2 = b_rel2[j];

    float wr2[D_H], wt2[D_H];
    #pragma unroll
    for (int k = 0; k < D_H; ++k) {
        wr2[k] = W_rel2[j*D_H + k];
        wt2[k] = W_root2[j*D_H + k];
    }

    for (int tt = 0; tt < TB; ++tt) {
        const int t = t0 + tt;
        __syncthreads();

        const float* xt = x + (size_t)t * (N_NODES * DIM_IN);
        for (int i = j; i < N_NODES * DIM_IN; i += 64) x_s[0][i] = xt[i];
        __syncthreads();

        if (j < N_NODES) {
            float a0 = 0.f, a1 = 0.f, a2 = 0.f;
            for (int e = 0; e < N_EDGES; ++e) {
                if (ed[e] == j) {
                    a0 += x_s[es[e]][0];
                    a1 += x_s[es[e]][1];
                    a2 += x_s[es[e]][2];
                }
            }
            agg1[j][0] = a0; agg1[j][1] = a1; agg1[j][2] = a2;
        }
        __syncthreads();

        for (int n = 0; n < N_NODES; ++n) {
            float v = br1
                + agg1[n][0]*wr1_0 + agg1[n][1]*wr1_1 + agg1[n][2]*wr1_2
                + x_s[n][0]*wt1_0  + x_s[n][1]*wt1_1  + x_s[n][2]*wt1_2;
            h1[n][j]  = v;
            agg2[n][j] = 0.f;
        }
        __syncthreads();

        for (int e = 0; e < N_EDGES; ++e) {
            agg2[ed[e]][j] += h1[es[e]][j];
        }
        __syncthreads();

        float seqv = 0.f;
        for (int n = 0; n < N_NODES; ++n) {
            const float4* ag4 = (const float4*)agg2[n];
            const float4* h4  = (const float4*)h1[n];
            float acc0 = br2, acc1 = 0.f, acc2 = 0.f, acc3 = 0.f;
            #pragma unroll
            for (int k4 = 0; k4 < D_H/4; ++k4) {
                float4 av = ag4[k4];
                float4 hv = h4[k4];
                acc0 += av.x * wr2[4*k4+0] + hv.x * wt2[4*k4+0];
                acc1 += av.y * wr2[4*k4+1] + hv.y * wt2[4*k4+1];
                acc2 += av.z * wr2[4*k4+2] + hv.z * wt2[4*k4+2];
                acc3 += av.w * wr2[4*k4+3] + hv.w * wt2[4*k4+3];
            }
            float acc = (acc0 + acc1) + (acc2 + acc3);
            seqv += fmaxf(acc, 0.f);
        }
        seq_s[tt][j] = seqv * (1.0f / 33.0f);
    }
    __syncthreads();

    #pragma unroll
    for (int m = 0; m < 8; ++m) {
        const int o = m * 64 + j;
        const float bias = b_ih[o] + b_hh[o];
        const float4* w4 = (const float4*)(W_ih + (size_t)o * D_H);
        float acc[TB];
        #pragma unroll
        for (int tt = 0; tt < TB; ++tt) acc[tt] = bias;
        #pragma unroll
        for (int k4 = 0; k4 < D_H/4; ++k4) {
            float4 wv = w4[k4];
            #pragma unroll
            for (int tt = 0; tt < TB; ++tt) {
                const float4* s4 = (const float4*)seq_s[tt];
                float4 sv = s4[k4];
                acc[tt] += sv.x*wv.x + sv.y*wv.y + sv.z*wv.z + sv.w*wv.w;
            }
        }
        #pragma unroll
        for (int tt = 0; tt < TB; ++tt) {
            A[(size_t)(t0 + tt) * 512 + o] = acc[tt];
        }
    }
}

// ---------------------------------------------------------------------------
// Kernel 2: sequential LSTM, single block (1 CU), 512 threads = 8 waves,
// 2 waves/SIMD (256-VGPR budget via waves_per_eu(2,2)).
//
// Thread (q, kq): all 4 gate rows of h_q {q,128+q,256+q,384+q} x K-chunk
// [32*kq, 32*kq+32), kq = tid&3 (quad lanes), idx = (tid>>2)&15,
// q = wave*16 + idx.
// Weights: 32 named float4 = 128 VGPRs (pinned). Demand ~185 < 256 budget.
// K-reduce over 4 kq = 2 quad_perm DPP stages (VALU, no LDS, no row ops).
// Nonlinearity branchless-replicated in all 4 quad lanes (c replicated,
// deterministic); only kq==0 writes h. ONE barrier per step.
// h LDS layout interleaved: h[k] (c=k>>2=kq*8+i, j=k&3) lives at float4
// slot p = i*4+kq  ->  read instr i touches 4 consecutive 16B chunks
// (16 distinct banks, 16-lane broadcasts) = conflict-free; read addr is
// simply hb[i*4 + kq].
// A prefetch: running pointer + immediate offsets {0,128,256,384}.
// ---------------------------------------------------------------------------
__device__ __forceinline__ float sigmoid_f(float v) {
    return 1.0f / (1.0f + __expf(-v));
}
__device__ __forceinline__ float tanh_f(float v) {
    return 1.0f - 2.0f / (1.0f + __expf(2.0f * v));
}

// quad_perm butterfly adds (cheapest DPP, within-quad, no row crossing)
__device__ __forceinline__ float qp_add_x1(float v) {   // lane ^ 1
    int s = __builtin_amdgcn_update_dpp(0, __float_as_int(v), 0xB1, 0xf, 0xf, true);
    return v + __int_as_float(s);
}
__device__ __forceinline__ float qp_add_x2(float v) {   // lane ^ 2
    int s = __builtin_amdgcn_update_dpp(0, __float_as_int(v), 0x4E, 0xf, 0xf, true);
    return v + __int_as_float(s);
}
__device__ __forceinline__ float red4(float v) {
    return qp_add_x2(qp_add_x1(v));
}

#define R8(M) M(0) M(1) M(2) M(3) M(4) M(5) M(6) M(7)

__global__ __launch_bounds__(512, 2)
__attribute__((amdgpu_waves_per_eu(2, 2)))
void lstm_kernel(
    const float* __restrict__ A,      // (T,512)
    const float* __restrict__ W_hh,   // (512,128)
    const float* __restrict__ W_fc,   // (5,128)
    const float* __restrict__ b_fc,   // (5,)
    float* __restrict__ out)          // (5,)
{
    const int tid  = threadIdx.x;            // 0..511
    const int wave = tid >> 6;               // 0..7
    const int kq   = tid & 3;                // quad lane = K-chunk id
    const int idx  = (tid >> 2) & 15;
    const int q    = wave * 16 + idx;        // h index 0..127
    const int kbase = kq * 32;               // K-chunk start

    __shared__ __align__(16) float h_s[2][D_LSTM];   // interleaved layout, dbuf

    // ---- weights: 4 gate rows x 32 K = 32 named float4 (128 VGPRs), pinned ----
    const float4* Wi4 = (const float4*)(W_hh + (size_t)q          * D_LSTM + kbase);
    const float4* Wf4 = (const float4*)(W_hh + (size_t)(128 + q)  * D_LSTM + kbase);
    const float4* Wg4 = (const float4*)(W_hh + (size_t)(256 + q)  * D_LSTM + kbase);
    const float4* Wo4 = (const float4*)(W_hh + (size_t)(384 + q)  * D_LSTM + kbase);
#define DECLW(i) float4 wi##i = Wi4[i]; float4 wf##i = Wf4[i]; \
                 float4 wg##i = Wg4[i]; float4 wo##i = Wo4[i];
    R8(DECLW)
#undef DECLW
#define PINW(i) asm volatile("" : "+v"(wi##i.x), "+v"(wi##i.y), "+v"(wi##i.z), "+v"(wi##i.w), \
                                  "+v"(wf##i.x), "+v"(wf##i.y), "+v"(wf##i.z), "+v"(wf##i.w), \
                                  "+v"(wg##i.x), "+v"(wg##i.y), "+v"(wg##i.z), "+v"(wg##i.w), \
                                  "+v"(wo##i.x), "+v"(wo##i.y), "+v"(wo##i.z), "+v"(wo##i.w));
    R8(PINW)
#undef PINW

    if (tid < 2 * D_LSTM) ((float*)h_s)[tid] = 0.f;   // h_{-1} = 0 (both bufs)
    __syncthreads();

    float c = 0.f;                      // replicated across the quad

    // prefetch A[0]; Ap tracks the NEXT row to load
    const float* Aq = A + q;
    float ai = Aq[0];
    float af = Aq[128];
    float ag = Aq[256];
    float ao = Aq[384];
    const float* Ap = Aq + 512;         // row 1

    for (int t = 0; t < T_LEN; ++t) {
        const float ai_c = ai, af_c = af, ag_c = ag, ao_c = ao;
        // prefetch next row (immediate offsets; hidden under the FMA block)
        ai = Ap[0];
        af = Ap[128];
        ag = Ap[256];
        ao = Ap[384];
        Ap = (t == T_LEN - 2) ? Aq : Ap + 512;   // wrap keeps loads in-bounds

        // ---- conflict-free broadcast reads of this thread's h chunk ----
        const float4* hb = (const float4*)h_s[t & 1];
        float4 hv0 = hb[0*4 + kq];
        float4 hv1 = hb[1*4 + kq];
        float4 hv2 = hb[2*4 + kq];
        float4 hv3 = hb[3*4 + kq];
        float4 hv4 = hb[4*4 + kq];
        float4 hv5 = hb[5*4 + kq];
        float4 hv6 = hb[6*4 + kq];
        float4 hv7 = hb[7*4 + kq];

        // ---- 128 FMAs: 4 gates x 32 K (4 independent chains) ----
        float pi = 0.f, pf = 0.f, pg = 0.f, po = 0.f;
#define FMA4(hv, i) \
        pi = __builtin_fmaf(hv.x, wi##i.x, pi); pf = __builtin_fmaf(hv.x, wf##i.x, pf); \
        pg = __builtin_fmaf(hv.x, wg##i.x, pg); po = __builtin_fmaf(hv.x, wo##i.x, po); \
        pi = __builtin_fmaf(hv.y, wi##i.y, pi); pf = __builtin_fmaf(hv.y, wf##i.y, pf); \
        pg = __builtin_fmaf(hv.y, wg##i.y, pg); po = __builtin_fmaf(hv.y, wo##i.y, po); \
        pi = __builtin_fmaf(hv.z, wi##i.z, pi); pf = __builtin_fmaf(hv.z, wf##i.z, pf); \
        pg = __builtin_fmaf(hv.z, wg##i.z, pg); po = __builtin_fmaf(hv.z, wo##i.z, po); \
        pi = __builtin_fmaf(hv.w, wi##i.w, pi); pf = __builtin_fmaf(hv.w, wf##i.w, pf); \
        pg = __builtin_fmaf(hv.w, wg##i.w, pg); po = __builtin_fmaf(hv.w, wo##i.w, po);
        FMA4(hv0, 0) FMA4(hv1, 1) FMA4(hv2, 2) FMA4(hv3, 3)
        FMA4(hv4, 4) FMA4(hv5, 5) FMA4(hv6, 6) FMA4(hv7, 7)
#undef FMA4

        // ---- K-reduce over the quad: 2 DPP stages, result in all 4 lanes ----
        const float gi = ai_c + red4(pi);
        const float gf = af_c + red4(pf);
        const float gg = ag_c + red4(pg);
        const float go = ao_c + red4(po);

        // ---- nonlinearity: replicated in all quad lanes (no divergence) ----
        const float si = sigmoid_f(gi);
        const float sf = sigmoid_f(gf);
        const float so = sigmoid_f(go);
        const float tg = tanh_f(gg);
        c = sf * c + si * tg;
        const float hv = so * tanh_f(c);

        // only kq==0 writes h_q (interleaved position)
        if (kq == 0) {
            const int cc = q >> 2;                       // chunk 0..31
            const int p  = ((cc & 7) << 2) | (cc >> 3);  // interleaved slot
            h_s[(t + 1) & 1][p * 4 + (q & 3)] = hv;
        }
        __syncthreads();    // ONE barrier per step (dbuf covers W-after-R)
    }

    // final FC: out = hT @ W_fc.T + b_fc  (final h in buffer 0, interleaved)
    if (tid < N_CLS) {
        float acc = b_fc[tid];
        #pragma unroll
        for (int k = 0; k < D_LSTM; ++k) {
            const int cc = k >> 2;
            const int p  = ((cc & 7) << 2) | (cc >> 3);
            acc += h_s[0][p * 4 + (k & 3)] * W_fc[tid * D_LSTM + k];
        }
        out[tid] = acc;
    }
}

// ---------------------------------------------------------------------------
extern "C" void kernel_launch(void* const* d_in, const int* in_sizes, int n_in,
                              void* d_out, int out_size, void* d_ws, size_t ws_size,
                              hipStream_t stream) {
    const float* x       = (const float*)d_in[0];
    const int*   esrc    = (const int*)  d_in[1];
    const int*   edst    = (const int*)  d_in[2];
    const float* W_rel1  = (const float*)d_in[3];
    const float* b_rel1  = (const float*)d_in[4];
    const float* W_root1 = (const float*)d_in[5];
    const float* W_rel2  = (const float*)d_in[6];
    const float* b_rel2  = (const float*)d_in[7];
    const float* W_root2 = (const float*)d_in[8];
    const float* W_ih    = (const float*)d_in[9];
    const float* W_hh    = (const float*)d_in[10];
    const float* b_ih    = (const float*)d_in[11];
    const float* b_hh    = (const float*)d_in[12];
    const float* W_fc    = (const float*)d_in[13];
    const float* b_fc    = (const float*)d_in[14];

    float* out = (float*)d_out;
    float* A   = (float*)d_ws;   // (T,512) f32 = 16 MB

    gnn_proj_kernel<<<T_LEN / TB, 64, 0, stream>>>(
        x, esrc, edst, W_rel1, b_rel1, W_root1,
        W_rel2, b_rel2, W_root2, W_ih, b_ih, b_hh, A);

    lstm_kernel<<<1, 512, 0, stream>>>(A, W_hh, W_fc, b_fc, out);
}

// Round 7
// 6564.474 us; speedup vs baseline: 1.4242x; 1.3416x over previous
//
#include <hip/hip_runtime.h>

#define T_LEN 8192
#define N_NODES 33
#define N_EDGES 64
#define DIM_IN 3
#define D_H 64
#define D_LSTM 128
#define N_CLS 5
#define TB 4   // timesteps per block in kernel 1

typedef float v2f __attribute__((ext_vector_type(2)));
typedef float v4f __attribute__((ext_vector_type(4)));

// ---------------------------------------------------------------------------
// Kernel 1: graph conv x2 + relu + mean over nodes + input-side LSTM projection
// Writes A in (T, 128, 4) layout: A[(t*128+q)*4 + g] = gate g of unit q
// (g: 0=i, 1=f, 2=g, 3=o), so the LSTM prefetch is ONE dwordx4 per thread.
// ---------------------------------------------------------------------------
__global__ __launch_bounds__(64, 2) void gnn_proj_kernel(
    const float* __restrict__ x,        // (T,33,3)
    const int*   __restrict__ esrc,     // (64,)
    const int*   __restrict__ edst,     // (64,)
    const float* __restrict__ W_rel1,   // (64,3)
    const float* __restrict__ b_rel1,   // (64,)
    const float* __restrict__ W_root1,  // (64,3)
    const float* __restrict__ W_rel2,   // (64,64)
    const float* __restrict__ b_rel2,   // (64,)
    const float* __restrict__ W_root2,  // (64,64)
    const float* __restrict__ W_ih,     // (512,64)
    const float* __restrict__ b_ih,     // (512,)
    const float* __restrict__ b_hh,     // (512,)
    float* __restrict__ A)              // (T,128,4)  [workspace]
{
    const int t0 = blockIdx.x * TB;
    const int j  = threadIdx.x;   // 0..63

    __shared__ __align__(16) float x_s[N_NODES][DIM_IN];
    __shared__ __align__(16) float agg1[N_NODES][DIM_IN];
    __shared__ __align__(16) float h1[N_NODES][D_H];
    __shared__ __align__(16) float agg2[N_NODES][D_H];
    __shared__ __align__(16) float seq_s[TB][D_H];
    __shared__ int es[N_EDGES], ed[N_EDGES];

    es[j] = esrc[j];
    ed[j] = edst[j];

    const float wr1_0 = W_rel1[j*3+0], wr1_1 = W_rel1[j*3+1], wr1_2 = W_rel1[j*3+2];
    const float wt1_0 = W_root1[j*3+0], wt1_1 = W_root1[j*3+1], wt1_2 = W_root1[j*3+2];
    const float br1 = b_rel1[j];
    const float br2 = b_rel2[j];

    float wr2[D_H], wt2[D_H];
    #pragma unroll
    for (int k = 0; k < D_H; ++k) {
        wr2[k] = W_rel2[j*D_H + k];
        wt2[k] = W_root2[j*D_H + k];
    }

    for (int tt = 0; tt < TB; ++tt) {
        const int t = t0 + tt;
        __syncthreads();

        const float* xt = x + (size_t)t * (N_NODES * DIM_IN);
        for (int i = j; i < N_NODES * DIM_IN; i += 64) x_s[0][i] = xt[i];
        __syncthreads();

        if (j < N_NODES) {
            float a0 = 0.f, a1 = 0.f, a2 = 0.f;
            for (int e = 0; e < N_EDGES; ++e) {
                if (ed[e] == j) {
                    a0 += x_s[es[e]][0];
                    a1 += x_s[es[e]][1];
                    a2 += x_s[es[e]][2];
                }
            }
            agg1[j][0] = a0; agg1[j][1] = a1; agg1[j][2] = a2;
        }
        __syncthreads();

        for (int n = 0; n < N_NODES; ++n) {
            float v = br1
                + agg1[n][0]*wr1_0 + agg1[n][1]*wr1_1 + agg1[n][2]*wr1_2
                + x_s[n][0]*wt1_0  + x_s[n][1]*wt1_1  + x_s[n][2]*wt1_2;
            h1[n][j]  = v;
            agg2[n][j] = 0.f;
        }
        __syncthreads();

        for (int e = 0; e < N_EDGES; ++e) {
            agg2[ed[e]][j] += h1[es[e]][j];
        }
        __syncthreads();

        float seqv = 0.f;
        for (int n = 0; n < N_NODES; ++n) {
            const float4* ag4 = (const float4*)agg2[n];
            const float4* h4  = (const float4*)h1[n];
            float acc0 = br2, acc1 = 0.f, acc2 = 0.f, acc3 = 0.f;
            #pragma unroll
            for (int k4 = 0; k4 < D_H/4; ++k4) {
                float4 av = ag4[k4];
                float4 hv = h4[k4];
                acc0 += av.x * wr2[4*k4+0] + hv.x * wt2[4*k4+0];
                acc1 += av.y * wr2[4*k4+1] + hv.y * wt2[4*k4+1];
                acc2 += av.z * wr2[4*k4+2] + hv.z * wt2[4*k4+2];
                acc3 += av.w * wr2[4*k4+3] + hv.w * wt2[4*k4+3];
            }
            float acc = (acc0 + acc1) + (acc2 + acc3);
            seqv += fmaxf(acc, 0.f);
        }
        seq_s[tt][j] = seqv * (1.0f / 33.0f);
    }
    __syncthreads();

    #pragma unroll
    for (int m = 0; m < 8; ++m) {
        const int o = m * 64 + j;
        const float bias = b_ih[o] + b_hh[o];
        const float4* w4 = (const float4*)(W_ih + (size_t)o * D_H);
        float acc[TB];
        #pragma unroll
        for (int tt = 0; tt < TB; ++tt) acc[tt] = bias;
        #pragma unroll
        for (int k4 = 0; k4 < D_H/4; ++k4) {
            float4 wv = w4[k4];
            #pragma unroll
            for (int tt = 0; tt < TB; ++tt) {
                const float4* s4 = (const float4*)seq_s[tt];
                float4 sv = s4[k4];
                acc[tt] += sv.x*wv.x + sv.y*wv.y + sv.z*wv.z + sv.w*wv.w;
            }
        }
        // (T,128,4) layout: q = o&127, g = o>>7
        #pragma unroll
        for (int tt = 0; tt < TB; ++tt) {
            A[((size_t)(t0 + tt) * 128 + (o & 127)) * 4 + (o >> 7)] = acc[tt];
        }
    }
}

// ---------------------------------------------------------------------------
// Kernel 2: sequential LSTM, single block (1 CU), 512 threads = 8 waves,
// 2 waves/SIMD.  Thread (q, kq): all 4 gate rows of h_q x K-chunk
// [32*kq, 32*kq+32).  Weights as 64 named v2f (128 VGPRs).
// Inner product = inline-asm v_pk_fma_f32 (packed 2xf32 FMA): halves the FMA
// instruction count AND forces every operand into arch VGPRs at every use,
// so the allocator cannot home weights in AGPRs with copy-per-use (the
// rounds-3..6 failure mode).  K-reduce = 2 quad_perm DPP stages.
// Nonlinearity quad-replicated (no divergence); kq==0 writes h.
// h LDS layout interleaved (conflict-free, verified r6); ONE barrier/step.
// A prefetch = ONE dwordx4 per thread from the (T,128,4) layout.
// ---------------------------------------------------------------------------
__device__ __forceinline__ float sigmoid_f(float v) {
    return 1.0f / (1.0f + __expf(-v));
}
__device__ __forceinline__ float tanh_f(float v) {
    return 1.0f - 2.0f / (1.0f + __expf(2.0f * v));
}

__device__ __forceinline__ float qp_add_x1(float v) {   // lane ^ 1
    int s = __builtin_amdgcn_update_dpp(0, __float_as_int(v), 0xB1, 0xf, 0xf, true);
    return v + __int_as_float(s);
}
__device__ __forceinline__ float qp_add_x2(float v) {   // lane ^ 2
    int s = __builtin_amdgcn_update_dpp(0, __float_as_int(v), 0x4E, 0xf, 0xf, true);
    return v + __int_as_float(s);
}
__device__ __forceinline__ float red4(float v) {
    return qp_add_x2(qp_add_x1(v));
}

// packed FMA: acc.xy += h.xy * w.xy   (VOP3P, forces arch-VGPR operands)
#define PKFMA(acc, h, w) \
    asm("v_pk_fma_f32 %0, %1, %2, %0" : "+v"(acc) : "v"(h), "v"(w))

#define R16(M) M(0) M(1) M(2) M(3) M(4) M(5) M(6) M(7) \
               M(8) M(9) M(10) M(11) M(12) M(13) M(14) M(15)

__global__ __launch_bounds__(512, 2)
__attribute__((amdgpu_waves_per_eu(2, 2)))
void lstm_kernel(
    const float* __restrict__ A,      // (T,128,4)
    const float* __restrict__ W_hh,   // (512,128)
    const float* __restrict__ W_fc,   // (5,128)
    const float* __restrict__ b_fc,   // (5,)
    float* __restrict__ out)          // (5,)
{
    const int tid  = threadIdx.x;            // 0..511
    const int wave = tid >> 6;               // 0..7
    const int kq   = tid & 3;                // quad lane = K-chunk id
    const int idx  = (tid >> 2) & 15;
    const int q    = wave * 16 + idx;        // h index 0..127
    const int kbase = kq * 32;               // K-chunk start

    __shared__ __align__(16) float h_s[2][D_LSTM];   // interleaved layout, dbuf

    // ---- weights: 4 gate rows x 32 K = 64 named v2f (128 VGPRs) ----
    const v2f* Wi2 = (const v2f*)(W_hh + (size_t)q          * D_LSTM + kbase);
    const v2f* Wf2 = (const v2f*)(W_hh + (size_t)(128 + q)  * D_LSTM + kbase);
    const v2f* Wg2 = (const v2f*)(W_hh + (size_t)(256 + q)  * D_LSTM + kbase);
    const v2f* Wo2 = (const v2f*)(W_hh + (size_t)(384 + q)  * D_LSTM + kbase);
#define DECLW(i) v2f wi##i = Wi2[i]; v2f wf##i = Wf2[i]; \
                 v2f wg##i = Wg2[i]; v2f wo##i = Wo2[i];
    R16(DECLW)
#undef DECLW
#define PINW(i) asm volatile("" : "+v"(wi##i), "+v"(wf##i), "+v"(wg##i), "+v"(wo##i));
    R16(PINW)
#undef PINW

    if (tid < 2 * D_LSTM) ((float*)h_s)[tid] = 0.f;   // h_{-1} = 0 (both bufs)
    __syncthreads();

    float c = 0.f;                      // replicated across the quad

    // prefetch A[0]; one float4 per thread; Ap tracks the NEXT row
    const v4f* A4 = (const v4f*)A;
    const v4f* Aq = A4 + q;
    v4f an = Aq[0];
    const v4f* Ap = Aq + 128;           // row 1

    for (int t = 0; t < T_LEN; ++t) {
        const v4f a_c = an;
        an = Ap[0];                               // prefetch next step
        Ap = (t == T_LEN - 2) ? Aq : Ap + 128;    // wrap keeps loads in-bounds

        // ---- conflict-free broadcast reads of this thread's h chunk ----
        const v4f* hb = (const v4f*)h_s[t & 1];
        v4f hv0 = hb[0*4 + kq];
        v4f hv1 = hb[1*4 + kq];
        v4f hv2 = hb[2*4 + kq];
        v4f hv3 = hb[3*4 + kq];
        v4f hv4 = hb[4*4 + kq];
        v4f hv5 = hb[5*4 + kq];
        v4f hv6 = hb[6*4 + kq];
        v4f hv7 = hb[7*4 + kq];

        // halves as v2f (subregister extracts, no moves)
        v2f h0  = __builtin_shufflevector(hv0, hv0, 0, 1);
        v2f h1  = __builtin_shufflevector(hv0, hv0, 2, 3);
        v2f h2  = __builtin_shufflevector(hv1, hv1, 0, 1);
        v2f h3  = __builtin_shufflevector(hv1, hv1, 2, 3);
        v2f h4  = __builtin_shufflevector(hv2, hv2, 0, 1);
        v2f h5  = __builtin_shufflevector(hv2, hv2, 2, 3);
        v2f h6  = __builtin_shufflevector(hv3, hv3, 0, 1);
        v2f h7  = __builtin_shufflevector(hv3, hv3, 2, 3);
        v2f h8  = __builtin_shufflevector(hv4, hv4, 0, 1);
        v2f h9  = __builtin_shufflevector(hv4, hv4, 2, 3);
        v2f h10 = __builtin_shufflevector(hv5, hv5, 0, 1);
        v2f h11 = __builtin_shufflevector(hv5, hv5, 2, 3);
        v2f h12 = __builtin_shufflevector(hv6, hv6, 0, 1);
        v2f h13 = __builtin_shufflevector(hv6, hv6, 2, 3);
        v2f h14 = __builtin_shufflevector(hv7, hv7, 0, 1);
        v2f h15 = __builtin_shufflevector(hv7, hv7, 2, 3);

        // ---- 64 packed FMAs: 4 gates x 32 K ----
        v2f ci = {0.f, 0.f}, cf = {0.f, 0.f}, cg = {0.f, 0.f}, co = {0.f, 0.f};
#define PK4(i) PKFMA(ci, h##i, wi##i); PKFMA(cf, h##i, wf##i); \
               PKFMA(cg, h##i, wg##i); PKFMA(co, h##i, wo##i);
        R16(PK4)
#undef PK4

        // ---- fold packed halves + K-reduce over the quad (DPP) ----
        const float gi = a_c.x + red4(ci.x + ci.y);
        const float gf = a_c.y + red4(cf.x + cf.y);
        const float gg = a_c.z + red4(cg.x + cg.y);
        const float go = a_c.w + red4(co.x + co.y);

        // ---- nonlinearity: replicated in all quad lanes (no divergence) ----
        const float si = sigmoid_f(gi);
        const float sf = sigmoid_f(gf);
        const float so = sigmoid_f(go);
        const float tg = tanh_f(gg);
        c = sf * c + si * tg;
        const float hv = so * tanh_f(c);

        // only kq==0 writes h_q (interleaved position)
        if (kq == 0) {
            const int cc = q >> 2;                       // chunk 0..31
            const int p  = ((cc & 7) << 2) | (cc >> 3);  // interleaved slot
            h_s[(t + 1) & 1][p * 4 + (q & 3)] = hv;
        }
        __syncthreads();    // ONE barrier per step (dbuf covers W-after-R)
    }

    // final FC: out = hT @ W_fc.T + b_fc  (final h in buffer 0, interleaved)
    if (tid < N_CLS) {
        float acc = b_fc[tid];
        #pragma unroll
        for (int k = 0; k < D_LSTM; ++k) {
            const int cc = k >> 2;
            const int p  = ((cc & 7) << 2) | (cc >> 3);
            acc += h_s[0][p * 4 + (k & 3)] * W_fc[tid * D_LSTM + k];
        }
        out[tid] = acc;
    }
}

// ---------------------------------------------------------------------------
extern "C" void kernel_launch(void* const* d_in, const int* in_sizes, int n_in,
                              void* d_out, int out_size, void* d_ws, size_t ws_size,
                              hipStream_t stream) {
    const float* x       = (const float*)d_in[0];
    const int*   esrc    = (const int*)  d_in[1];
    const int*   edst    = (const int*)  d_in[2];
    const float* W_rel1  = (const float*)d_in[3];
    const float* b_rel1  = (const float*)d_in[4];
    const float* W_root1 = (const float*)d_in[5];
    const float* W_rel2  = (const float*)d_in[6];
    const float* b_rel2  = (const float*)d_in[7];
    const float* W_root2 = (const float*)d_in[8];
    const float* W_ih    = (const float*)d_in[9];
    const float* W_hh    = (const float*)d_in[10];
    const float* b_ih    = (const float*)d_in[11];
    const float* b_hh    = (const float*)d_in[12];
    const float* W_fc    = (const float*)d_in[13];
    const float* b_fc    = (const float*)d_in[14];

    float* out = (float*)d_out;
    float* A   = (float*)d_ws;   // (T,128,4) f32 = 16 MB

    gnn_proj_kernel<<<T_LEN / TB, 64, 0, stream>>>(
        x, esrc, edst, W_rel1, b_rel1, W_root1,
        W_rel2, b_rel2, W_root2, W_ih, b_ih, b_hh, A);

    lstm_kernel<<<1, 512, 0, stream>>>(A, W_hh, W_fc, b_fc, out);
}